// Round 6
// baseline (322.176 us; speedup 1.0000x reference)
//
#include <hip/hip_runtime.h>

#define DEV __device__ __forceinline__

using bf16x8 = __attribute__((ext_vector_type(8))) __bf16;
using f32x4  = __attribute__((ext_vector_type(4))) float;
typedef unsigned int u32;
typedef unsigned short u16;
typedef unsigned long long u64;

static constexpr int Bb = 4, Ss = 1024, Ee = 1024, Hh = 16, Dd = 64, Ff = 4096;
static constexpr int Mm = Bb * Ss; // 4096 rows

// ---------- helpers ----------
DEV u16 f2bf(float f) {                 // fp32 -> bf16 RNE (finite inputs)
  union { float f; u32 u; } v; v.f = f;
  u32 r = v.u + 0x7fffu + ((v.u >> 16) & 1u);
  return (u16)(r >> 16);
}

DEV void gload16(const void* g, void* lds) {   // async global->LDS, 16B/lane
  __builtin_amdgcn_global_load_lds(
      (const __attribute__((address_space(1))) void*)(u64)g,
      (__attribute__((address_space(3))) void*)(u32)(u64)lds,
      16, 0, 0);
}

DEV float gelu_tanh(float x) {          // gelu_new (tanh approx)
  float x3 = x * x * x;
  float t  = tanhf(0.7978845608028654f * (x + 0.044715f * x3));
  return 0.5f * x * (1.0f + t);
}

// XOR-swizzle for [R][64] bf16 LDS tiles (attention): 16B-slot ^= row&7
DEV int swz(int row, int col) { return row * 64 + (col ^ ((row & 7) << 3)); }

DEV f32x4 MFMA(bf16x8 a, bf16x8 b, f32x4 c) {
  return __builtin_amdgcn_mfma_f32_16x16x32_bf16(a, b, c, 0, 0, 0);
}

// ---------- fp32 -> bf16 convert (8 elems/thread) ----------
__global__ __launch_bounds__(256) void cvt_bf16(const float* __restrict__ in,
                                                u16* __restrict__ out, int n) {
  int i = (blockIdx.x * 256 + threadIdx.x) * 8;
  if (i >= n) return;
  float4 a = *(const float4*)(in + i);
  float4 b = *(const float4*)(in + i + 4);
  uint4 o;
  o.x = (u32)f2bf(a.x) | ((u32)f2bf(a.y) << 16);
  o.y = (u32)f2bf(a.z) | ((u32)f2bf(a.w) << 16);
  o.z = (u32)f2bf(b.x) | ((u32)f2bf(b.y) << 16);
  o.w = (u32)f2bf(b.z) | ((u32)f2bf(b.w) << 16);
  *(uint4*)(out + i) = o;
}

// ---------- LayerNorm: one row (1024) per block, fp32 in -> bf16 out ----------
__global__ __launch_bounds__(256) void ln_kernel(const float* __restrict__ x,
                                                 const float* __restrict__ scale,
                                                 const float* __restrict__ bias,
                                                 u16* __restrict__ h) {
  const int row = blockIdx.x, tid = threadIdx.x;
  const float4 v = ((const float4*)(x + (size_t)row * Ee))[tid];
  float s  = v.x + v.y + v.z + v.w;
  float ss = v.x * v.x + v.y * v.y + v.z * v.z + v.w * v.w;
  for (int m = 1; m < 64; m <<= 1) {
    s  += __shfl_xor(s, m, 64);
    ss += __shfl_xor(ss, m, 64);
  }
  __shared__ float red[8];
  const int w = tid >> 6, ln = tid & 63;
  if (ln == 0) { red[w * 2] = s; red[w * 2 + 1] = ss; }
  __syncthreads();
  s  = red[0] + red[2] + red[4] + red[6];
  ss = red[1] + red[3] + red[5] + red[7];
  const float mu   = s * (1.0f / Ee);
  const float var  = ss * (1.0f / Ee) - mu * mu;
  const float rstd = rsqrtf(var + 1e-5f);
  const float4 sc = ((const float4*)scale)[tid];
  const float4 bi = ((const float4*)bias)[tid];
  ushort4 o;
  o.x = f2bf((v.x - mu) * rstd * sc.x + bi.x);
  o.y = f2bf((v.y - mu) * rstd * sc.y + bi.y);
  o.z = f2bf((v.z - mu) * rstd * sc.z + bi.z);
  o.w = f2bf((v.w - mu) * rstd * sc.w + bi.w);
  ((ushort4*)(h + (size_t)row * Ee))[tid] = o;
}

// ============ 256x256 8-phase GEMM (m201-faithful port), C = A @ B^T ========
// BM=BN=256, BK=64, 512 thr = 8 waves (2Mx4N), per-wave 128x64 output.
// LDS 128KB: per matrix 2 dbuf x 2 K-HALF sub-tiles [256][32] (16KB each).
// K-half split lets each phase's counted vmcnt(4) leave 2 halves in flight
// (never drain to 0 mid-loop) while every read is provably landed:
//   tile t, phase 0: read A.k0(m0-3)+B.k0 | stage (t+1).A.k0 | bar|lgkm|16 MFMA|bar
//   phase 1: read A.k0(m4-7)             | stage (t+1).B.k0 | ... vmcnt(4) bar
//   phase 2: read A.k1(m0-3)+B.k1        | stage (t+1).A.k1 | ... bar
//   phase 3: read A.k1(m4-7)             | stage (t+1).B.k1 | ... vmcnt(4) bar
// vmcnt(4)@ph1 drains t.k1 (read at ph2); vmcnt(4)@ph3 drains (t+1).k0.
// Guarantee point is vmcnt->barrier (covers all waves' loads).
// EPI: 0 = QKV split (+bias, q*0.125 -> [B,H,S,D] bf16); 2 = gelu(+bias)->bf16
template <int EPI>
__global__ __launch_bounds__(512, 2) void gemm8p(
    const u16* __restrict__ A, const u16* __restrict__ Bw,
    const float* __restrict__ bias,
    u16* __restrict__ outb,
    u16* __restrict__ q, u16* __restrict__ k, u16* __restrict__ v,
    int N, int K) {
  __shared__ u16 AS[2][2][256 * 32];   // [dbuf][khalf][256 rows][32 cols]
  __shared__ u16 BS[2][2][256 * 32];
  const int tid = threadIdx.x;
  const int w = tid >> 6, ln = tid & 63;
  const int lr = ln & 15, lg = ln >> 4;
  const int wr = w >> 2, wc = w & 3;

  // XCD bijective block swizzle (nwg % 8 == 0 for all grids used here)
  const int nwg = gridDim.x * gridDim.y;
  const int bid = blockIdx.y * gridDim.x + blockIdx.x;
  const int sid = (bid & 7) * (nwg >> 3) + (bid >> 3);
  const int bx = sid % gridDim.x, by = sid / gridDim.x;
  const int tm = by * 256, tn = bx * 256;

  f32x4 acc[8][4];
  f32x4 zero4 = {0.f, 0.f, 0.f, 0.f};
#pragma unroll
  for (int i = 0; i < 8; ++i)
#pragma unroll
    for (int j = 0; j < 4; ++j) acc[i][j] = zero4;

  // ---- staging: one K-half = [256][32] = 16KB = 2 gload16/thread.
  // chunk c (0..1023): row=c>>2, LDS slot=c&3; thread covers c=tid, c=512+tid
  // (rows srow and srow+128, same slot). Global source slot pre-swizzled:
  // gsl = slot ^ (row&3)  (2-bit swizzle; involution applied again on reads).
  const int srow = tid >> 2;
  const int gsl  = (tid & 3) ^ (srow & 3);
  const u16* aG = A  + (size_t)(tm + srow) * K + gsl * 8;
  const u16* bG = Bw + (size_t)(tn + srow) * K + gsl * 8;

  auto STG = [&](u16* lds, const u16* g, int koff) {
    gload16(g + koff, lds + tid * 8);
    gload16(g + (size_t)128 * K + koff, lds + 4096 + tid * 8);
  };

  // ---- fragment reads: element offset of 16B slot within a half-row
  const int fsl = (lg ^ (lr & 3)) << 3;
  const int aRow = wr * 128 + lr;     // + mi*16
  const int bRow = wc * 64 + lr;      // + n*16

  auto RD_A = [&](bf16x8* dst, const u16* half, int mh) {
#pragma unroll
    for (int i = 0; i < 4; ++i)
      dst[i] = *(const bf16x8*)&half[(aRow + (mh * 4 + i) * 16) * 32 + fsl];
  };
  auto RD_B = [&](bf16x8* dst, const u16* half) {
#pragma unroll
    for (int i = 0; i < 4; ++i)
      dst[i] = *(const bf16x8*)&half[(bRow + i * 16) * 32 + fsl];
  };
  auto MF16 = [&](int mh, const bf16x8* a, const bf16x8* b) {
    __builtin_amdgcn_s_setprio(1);
#pragma unroll
    for (int i = 0; i < 4; ++i)
#pragma unroll
      for (int n = 0; n < 4; ++n)
        acc[mh * 4 + i][n] = MFMA(a[i], b[n], acc[mh * 4 + i][n]);
    __builtin_amdgcn_s_setprio(0);
  };
  auto BAR = [&]() { __builtin_amdgcn_s_barrier(); };
  auto LGKM0 = [&]() {
    asm volatile("s_waitcnt lgkmcnt(0)" ::: "memory");
    __builtin_amdgcn_sched_barrier(0);
  };

  const int nkt = K >> 6;
  // ---- prologue: stage tile0 halves in order Ak0,Bk0,Ak1,Bk1 (8 loads);
  // vmcnt(4) -> k0 pair landed, k1 pair in flight (steady-state invariant).
  STG(&AS[0][0][0], aG, 0);
  STG(&BS[0][0][0], bG, 0);
  STG(&AS[0][1][0], aG, 32);
  STG(&BS[0][1][0], bG, 32);
  asm volatile("s_waitcnt vmcnt(4)" ::: "memory");
  BAR();

  for (int t = 0; t < nkt; ++t) {
    const int c = t & 1, nc = c ^ 1;
    const u16* A0 = &AS[c][0][0];
    const u16* A1 = &AS[c][1][0];
    const u16* B0 = &BS[c][0][0];
    const u16* B1 = &BS[c][1][0];
    const bool more = (t + 1) < nkt;
    const int koff = (t + 1) << 6;
    bf16x8 a[4], bk0[4], bk1[4];

    // ---- phase 0: (k0, m0-3)
    RD_A(a, A0, 0);
    RD_B(bk0, B0);
    if (more) STG(&AS[nc][0][0], aG, koff);          // (t+1) A.k0
    BAR(); LGKM0();
    MF16(0, a, bk0);
    BAR();

    // ---- phase 1: (k0, m4-7)
    RD_A(a, A0, 1);
    if (more) STG(&BS[nc][0][0], bG, koff);          // (t+1) B.k0
    BAR(); LGKM0();
    MF16(1, a, bk0);
    if (more) asm volatile("s_waitcnt vmcnt(4)" ::: "memory");  // t.k1 landed
    else      asm volatile("s_waitcnt vmcnt(0)" ::: "memory");
    BAR();

    // ---- phase 2: (k1, m0-3)
    RD_A(a, A1, 0);
    RD_B(bk1, B1);
    if (more) STG(&AS[nc][1][0], aG, koff + 32);     // (t+1) A.k1
    BAR(); LGKM0();
    MF16(0, a, bk1);
    BAR();

    // ---- phase 3: (k1, m4-7)
    RD_A(a, A1, 1);
    if (more) STG(&BS[nc][1][0], bG, koff + 32);     // (t+1) B.k1
    BAR(); LGKM0();
    MF16(1, a, bk1);
    if (more) asm volatile("s_waitcnt vmcnt(4)" ::: "memory");  // (t+1).k0 landed
    BAR();
  }

  // ---- epilogue
#pragma unroll
  for (int mi = 0; mi < 8; ++mi) {
#pragma unroll
    for (int ni = 0; ni < 4; ++ni) {
      const int gc = tn + wc * 64 + ni * 16 + lr;
#pragma unroll
      for (int j = 0; j < 4; ++j) {
        const int gr = tm + wr * 128 + mi * 16 + lg * 4 + j;
        float val = acc[mi][ni][j] + bias[gc];
        if constexpr (EPI == 0) {
          const int which = gc >> 10, hh = (gc >> 6) & 15, dd = gc & 63;
          const int bb2 = gr >> 10, ss2 = gr & 1023;
          const size_t dst = ((size_t)(bb2 * 16 + hh) * 1024 + ss2) * 64 + dd;
          if (which == 0)      q[dst] = f2bf(val * 0.125f);   // 1/sqrt(64)
          else if (which == 1) k[dst] = f2bf(val);
          else                 v[dst] = f2bf(val);
        } else {
          outb[(size_t)gr * N + gc] = f2bf(gelu_tanh(val));
        }
      }
    }
  }
}

// ---------- bf16 GEMM v2 (128x128, used for proj/proj2): C = A @ B^T --------
// EPI: 1 = +bias +resid(fp32) -> fp32
template <int EPI>
__global__ __launch_bounds__(256, 3) void gemm2(
    const u16* __restrict__ A, const u16* __restrict__ Bw,
    const float* __restrict__ bias, const float* __restrict__ resid,
    float* __restrict__ outf, u16* __restrict__ outb,
    u16* __restrict__ q, u16* __restrict__ k, u16* __restrict__ v,
    int N, int K) {
  __shared__ u16 As[3][128 * 32];   // 3 x 8KB
  __shared__ u16 Bs[3][128 * 32];   // 3 x 8KB  (48KB total)
  const int tid = threadIdx.x;
  const int w = tid >> 6, ln = tid & 63;
  const int lr = ln & 15, lg = ln >> 4;

  const int nwg = gridDim.x * gridDim.y;
  const int bid = blockIdx.y * gridDim.x + blockIdx.x;
  const int sid = (bid & 7) * (nwg >> 3) + (bid >> 3);
  const int bx = sid % gridDim.x, by = sid / gridDim.x;
  const int tm = by * 128, tn = bx * 128;
  const int wr = (w >> 1) * 64, wc = (w & 1) * 64;

  f32x4 zero4 = {0.f, 0.f, 0.f, 0.f};
  f32x4 acc[4][4];
#pragma unroll
  for (int i = 0; i < 4; ++i)
#pragma unroll
    for (int j = 0; j < 4; ++j) acc[i][j] = zero4;

  const int r0 = tid >> 2, sl = tid & 3;
  const int cs = (sl ^ (r0 & 3)) * 8;
  const u16* aP0 = A  + (size_t)(tm + r0) * K + cs;
  const u16* aP1 = A  + (size_t)(tm + 64 + r0) * K + cs;
  const u16* bP0 = Bw + (size_t)(tn + r0) * K + cs;
  const u16* bP1 = Bw + (size_t)(tn + 64 + r0) * K + cs;

  auto STAGE = [&](int buf, int k0) {
    gload16(aP0 + k0, &As[buf][tid * 8]);
    gload16(aP1 + k0, &As[buf][(256 + tid) * 8]);
    gload16(bP0 + k0, &Bs[buf][tid * 8]);
    gload16(bP1 + k0, &Bs[buf][(256 + tid) * 8]);
  };

  const int nt = K >> 5;
  STAGE(0, 0);
  STAGE(1, 32);
  asm volatile("s_waitcnt vmcnt(4)" ::: "memory");
  __builtin_amdgcn_s_barrier();
  __builtin_amdgcn_sched_barrier(0);

  for (int t = 0; t < nt; ++t) {
    const int cur = t % 3;
    const bool more = (t + 2) < nt;
    if (more) STAGE((t + 2) % 3, (t + 2) << 5);

    bf16x8 af[4], bb[4];
#pragma unroll
    for (int mi = 0; mi < 4; ++mi) {
      const int row = wr + mi * 16 + lr;
      af[mi] = *(const bf16x8*)&As[cur][row * 32 + ((lg ^ (row & 3)) << 3)];
    }
#pragma unroll
    for (int ni = 0; ni < 4; ++ni) {
      const int row = wc + ni * 16 + lr;
      bb[ni] = *(const bf16x8*)&Bs[cur][row * 32 + ((lg ^ (row & 3)) << 3)];
    }
    __builtin_amdgcn_s_setprio(1);
#pragma unroll
    for (int mi = 0; mi < 4; ++mi)
#pragma unroll
      for (int ni = 0; ni < 4; ++ni)
        acc[mi][ni] = MFMA(af[mi], bb[ni], acc[mi][ni]);
    __builtin_amdgcn_s_setprio(0);
    __builtin_amdgcn_sched_barrier(0);
    if (more) asm volatile("s_waitcnt vmcnt(4)" ::: "memory");
    else      asm volatile("s_waitcnt vmcnt(0)" ::: "memory");
    __builtin_amdgcn_s_barrier();
    __builtin_amdgcn_sched_barrier(0);
  }

#pragma unroll
  for (int mi = 0; mi < 4; ++mi) {
#pragma unroll
    for (int ni = 0; ni < 4; ++ni) {
      const int gc = tn + wc + ni * 16 + lr;
#pragma unroll
      for (int j = 0; j < 4; ++j) {
        const int gr = tm + wr + mi * 16 + lg * 4 + j;
        float val = acc[mi][ni][j] + bias[gc];
        if constexpr (EPI == 1) {
          const size_t idx = (size_t)gr * N + gc;
          outf[idx] = val + resid[idx];
        } else {
          outb[(size_t)gr * N + gc] = f2bf(gelu_tanh(val));
        }
      }
    }
  }
}

// ---------- flash attention (no mask). Q pre-scaled. [B,H,S,D] bf16 in ------
__global__ __launch_bounds__(256) void attn_kernel(const u16* __restrict__ qg,
                                                   const u16* __restrict__ kg,
                                                   const u16* __restrict__ vg,
                                                   u16* __restrict__ ao) {
  __shared__ u16 Qs[64 * 64], Ks[64 * 64], Vt[64 * 64], Ps[64 * 64];
  const int tid = threadIdx.x;
  const int w = tid >> 6, ln = tid & 63;
  const int lr = ln & 15, lg = ln >> 4;
  const int bh = blockIdx.y;
  const int q0 = blockIdx.x * 64;
  const size_t head = (size_t)bh * (Ss * Dd);

  { // stage Q (swizzled)
    const u16* src = qg + head + (size_t)q0 * Dd;
#pragma unroll
    for (int i = 0; i < 2; ++i) {
      const int gi = i * 256 + tid, row = gi >> 3, g = gi & 7;
      *(uint4*)&Qs[row * 64 + ((g ^ (row & 7)) << 3)] = *(const uint4*)(src + gi * 8);
    }
  }

  f32x4 zero4 = {0.f, 0.f, 0.f, 0.f};
  f32x4 acc_o[4] = {zero4, zero4, zero4, zero4};
  float mrow[4] = {-1e30f, -1e30f, -1e30f, -1e30f};
  float lrow[4] = {0.f, 0.f, 0.f, 0.f};

  for (int kt = 0; kt < 16; ++kt) {
    __syncthreads();
    const u16* ksrc = kg + head + (size_t)kt * 64 * Dd;
    const u16* vsrc = vg + head + (size_t)kt * 64 * Dd;
#pragma unroll
    for (int i = 0; i < 2; ++i) {
      const int gi = i * 256 + tid, row = gi >> 3, g = gi & 7;
      *(uint4*)&Ks[row * 64 + ((g ^ (row & 7)) << 3)] = *(const uint4*)(ksrc + gi * 8);
    }
#pragma unroll
    for (int i = 0; i < 2; ++i) {
      const int kv = i * 32 + (tid >> 3), d0 = (tid & 7) * 8;
      uint4 dv = *(const uint4*)(vsrc + (size_t)kv * Dd + d0);
      const u16* pv = (const u16*)&dv;
#pragma unroll
      for (int j = 0; j < 8; ++j) {
        const int dd = d0 + j;
        Vt[dd * 64 + (((kv >> 3) ^ (dd & 7)) << 3) + (kv & 7)] = pv[j];
      }
    }
    __syncthreads();

    bf16x8 aq[2];
#pragma unroll
    for (int kk = 0; kk < 2; ++kk)
      aq[kk] = *(const bf16x8*)&Qs[swz(w * 16 + lr, kk * 32 + lg * 8)];
    f32x4 sa[4];
#pragma unroll
    for (int kf = 0; kf < 4; ++kf) {
      f32x4 s = zero4;
#pragma unroll
      for (int kk = 0; kk < 2; ++kk) {
        bf16x8 bk = *(const bf16x8*)&Ks[swz(kf * 16 + lr, kk * 32 + lg * 8)];
        s = MFMA(aq[kk], bk, s);
      }
      sa[kf] = s;
    }

#pragma unroll
    for (int j = 0; j < 4; ++j) {
      float mx = fmaxf(fmaxf(sa[0][j], sa[1][j]), fmaxf(sa[2][j], sa[3][j]));
      mx = fmaxf(mx, __shfl_xor(mx, 1, 64));
      mx = fmaxf(mx, __shfl_xor(mx, 2, 64));
      mx = fmaxf(mx, __shfl_xor(mx, 4, 64));
      mx = fmaxf(mx, __shfl_xor(mx, 8, 64));
      const float nm = fmaxf(mrow[j], mx);
      const float corr = __expf(mrow[j] - nm);
      mrow[j] = nm;
      float ssum = 0.f;
#pragma unroll
      for (int kf = 0; kf < 4; ++kf) {
        const float p = __expf(sa[kf][j] - nm);
        sa[kf][j] = p;
        ssum += p;
      }
      ssum += __shfl_xor(ssum, 1, 64);
      ssum += __shfl_xor(ssum, 2, 64);
      ssum += __shfl_xor(ssum, 4, 64);
      ssum += __shfl_xor(ssum, 8, 64);
      lrow[j] = lrow[j] * corr + ssum;
#pragma unroll
      for (int df = 0; df < 4; ++df) acc_o[df][j] *= corr;
    }

#pragma unroll
    for (int kf = 0; kf < 4; ++kf)
#pragma unroll
      for (int j = 0; j < 4; ++j)
        Ps[swz(w * 16 + lg * 4 + j, kf * 16 + lr)] = f2bf(sa[kf][j]);

    __syncthreads();

    bf16x8 ap[2];
#pragma unroll
    for (int kk = 0; kk < 2; ++kk)
      ap[kk] = *(const bf16x8*)&Ps[swz(w * 16 + lr, kk * 32 + lg * 8)];
#pragma unroll
    for (int df = 0; df < 4; ++df) {
#pragma unroll
      for (int kk = 0; kk < 2; ++kk) {
        bf16x8 bv = *(const bf16x8*)&Vt[swz(df * 16 + lr, kk * 32 + lg * 8)];
        acc_o[df] = MFMA(ap[kk], bv, acc_o[df]);
      }
    }
  }

  const int b = bh >> 4, h = bh & 15;
#pragma unroll
  for (int df = 0; df < 4; ++df) {
#pragma unroll
    for (int j = 0; j < 4; ++j) {
      const int srow = q0 + w * 16 + lg * 4 + j;
      const int e = h * 64 + df * 16 + lr;
      ao[((size_t)b * Ss + srow) * Ee + e] = f2bf(acc_o[df][j] / lrow[j]);
    }
  }
}

// ---------- launcher ----------
extern "C" void kernel_launch(void* const* d_in, const int* in_sizes, int n_in,
                              void* d_out, int out_size, void* d_ws, size_t ws_size,
                              hipStream_t stream) {
  const float* x      = (const float*)d_in[0];
  const float* ln1_s  = (const float*)d_in[1];
  const float* ln1_b  = (const float*)d_in[2];
  const float* w_attn = (const float*)d_in[3];
  const float* b_attn = (const float*)d_in[4];
  const float* w_proj = (const float*)d_in[5];
  const float* b_proj = (const float*)d_in[6];
  const float* ln2_s  = (const float*)d_in[7];
  const float* ln2_b  = (const float*)d_in[8];
  const float* w_fc   = (const float*)d_in[9];
  const float* b_fc   = (const float*)d_in[10];
  const float* w_proj2= (const float*)d_in[11];
  const float* b_proj2= (const float*)d_in[12];
  float* out = (float*)d_out;

  char* base = (char*)d_ws;
  size_t off = 0;
  auto alloc = [&](size_t bytes) { char* p = base + off; off += bytes; return p; };
  u16* wA   = (u16*)alloc((size_t)3 * Ee * Ee * 2);  // 6 MB
  u16* wP   = (u16*)alloc((size_t)Ee * Ee * 2);      // 2 MB
  u16* wF   = (u16*)alloc((size_t)Ff * Ee * 2);      // 8 MB
  u16* wP2  = (u16*)alloc((size_t)Ee * Ff * 2);      // 8 MB
  u16* h1   = (u16*)alloc((size_t)Mm * Ee * 2);      // 8 MB (reused as h2)
  u16* qws  = (u16*)alloc((size_t)Mm * Ee * 2);      // 8 MB (q; mfc alias start)
  u16* kws  = (u16*)alloc((size_t)Mm * Ee * 2);      // 8 MB (k)
  u16* vws  = (u16*)alloc((size_t)Mm * Ee * 2);      // 8 MB (v)
  u16* aws  = (u16*)alloc((size_t)Mm * Ee * 2);      // 8 MB (attn out)
  float* x1 = (float*)alloc((size_t)Mm * Ee * 4);    // 16 MB
  u16* mfc  = qws;  // [4096,4096] bf16 aliases q/k/v/ao (all dead by then)

  // weights -> bf16 (every call; deterministic)
  cvt_bf16<<<3 * Ee * Ee / 2048, 256, 0, stream>>>(w_attn, wA, 3 * Ee * Ee);
  cvt_bf16<<<Ee * Ee / 2048, 256, 0, stream>>>(w_proj, wP, Ee * Ee);
  cvt_bf16<<<Ff * Ee / 2048, 256, 0, stream>>>(w_fc, wF, Ff * Ee);
  cvt_bf16<<<Ee * Ff / 2048, 256, 0, stream>>>(w_proj2, wP2, Ee * Ff);

  // LN1 -> h1
  ln_kernel<<<Mm, 256, 0, stream>>>(x, ln1_s, ln1_b, h1);
  // QKV GEMM (8-phase): [4096,1024]@[1024,3072]^T -> q,k,v [B,H,S,D]
  gemm8p<0><<<dim3(12, 16), 512, 0, stream>>>(h1, wA, b_attn,
                                              nullptr, qws, kws, vws,
                                              3 * Ee, Ee);
  // attention
  attn_kernel<<<dim3(16, 64), 256, 0, stream>>>(qws, kws, vws, aws);
  // proj + residual -> x1 (fp32)
  gemm2<1><<<dim3(8, 32), 256, 0, stream>>>(aws, wP, b_proj, x,
                                            x1, nullptr, nullptr, nullptr, nullptr,
                                            Ee, Ee);
  // LN2 -> h1 (as h2)
  ln_kernel<<<Mm, 256, 0, stream>>>(x1, ln2_s, ln2_b, h1);
  // fc + gelu -> mfc (bf16, 8-phase)
  gemm8p<2><<<dim3(16, 16), 512, 0, stream>>>(h1, wF, b_fc,
                                              mfc, nullptr, nullptr, nullptr,
                                              Ff, Ee);
  // proj2 + residual -> out (fp32)
  gemm2<1><<<dim3(8, 32), 256, 0, stream>>>(mfc, wP2, b_proj2, x1,
                                            out, nullptr, nullptr, nullptr, nullptr,
                                            Ee, Ff);
}

// Round 7
// 307.069 us; speedup vs baseline: 1.0492x; 1.0492x over previous
//
#include <hip/hip_runtime.h>

#define DEV __device__ __forceinline__

using bf16x8 = __attribute__((ext_vector_type(8))) __bf16;
using f32x4  = __attribute__((ext_vector_type(4))) float;
typedef unsigned int u32;
typedef unsigned short u16;
typedef unsigned long long u64;

static constexpr int Bb = 4, Ss = 1024, Ee = 1024, Hh = 16, Dd = 64, Ff = 4096;
static constexpr int Mm = Bb * Ss; // 4096 rows

// ---------- helpers ----------
DEV u16 f2bf(float f) {                 // fp32 -> bf16 RNE (finite inputs)
  union { float f; u32 u; } v; v.f = f;
  u32 r = v.u + 0x7fffu + ((v.u >> 16) & 1u);
  return (u16)(r >> 16);
}

DEV void gload16(const void* g, void* lds) {   // async global->LDS, 16B/lane
  __builtin_amdgcn_global_load_lds(
      (const __attribute__((address_space(1))) void*)(u64)g,
      (__attribute__((address_space(3))) void*)(u32)(u64)lds,
      16, 0, 0);
}

DEV float gelu_tanh(float x) {          // gelu_new (tanh approx)
  float x3 = x * x * x;
  float t  = tanhf(0.7978845608028654f * (x + 0.044715f * x3));
  return 0.5f * x * (1.0f + t);
}

// XOR-swizzle for [R][64] bf16 LDS tiles (attention): 16B-slot ^= row&7
DEV int swz(int row, int col) { return row * 64 + (col ^ ((row & 7) << 3)); }

DEV f32x4 MFMA(bf16x8 a, bf16x8 b, f32x4 c) {
  return __builtin_amdgcn_mfma_f32_16x16x32_bf16(a, b, c, 0, 0, 0);
}

// ---------- fp32 -> bf16 convert (8 elems/thread) ----------
__global__ __launch_bounds__(256) void cvt_bf16(const float* __restrict__ in,
                                                u16* __restrict__ out, int n) {
  int i = (blockIdx.x * 256 + threadIdx.x) * 8;
  if (i >= n) return;
  float4 a = *(const float4*)(in + i);
  float4 b = *(const float4*)(in + i + 4);
  uint4 o;
  o.x = (u32)f2bf(a.x) | ((u32)f2bf(a.y) << 16);
  o.y = (u32)f2bf(a.z) | ((u32)f2bf(a.w) << 16);
  o.z = (u32)f2bf(b.x) | ((u32)f2bf(b.y) << 16);
  o.w = (u32)f2bf(b.z) | ((u32)f2bf(b.w) << 16);
  *(uint4*)(out + i) = o;
}

// ---------- LayerNorm: one row (1024) per block, fp32 in -> bf16 out ----------
__global__ __launch_bounds__(256) void ln_kernel(const float* __restrict__ x,
                                                 const float* __restrict__ scale,
                                                 const float* __restrict__ bias,
                                                 u16* __restrict__ h) {
  const int row = blockIdx.x, tid = threadIdx.x;
  const float4 v = ((const float4*)(x + (size_t)row * Ee))[tid];
  float s  = v.x + v.y + v.z + v.w;
  float ss = v.x * v.x + v.y * v.y + v.z * v.z + v.w * v.w;
  for (int m = 1; m < 64; m <<= 1) {
    s  += __shfl_xor(s, m, 64);
    ss += __shfl_xor(ss, m, 64);
  }
  __shared__ float red[8];
  const int w = tid >> 6, ln = tid & 63;
  if (ln == 0) { red[w * 2] = s; red[w * 2 + 1] = ss; }
  __syncthreads();
  s  = red[0] + red[2] + red[4] + red[6];
  ss = red[1] + red[3] + red[5] + red[7];
  const float mu   = s * (1.0f / Ee);
  const float var  = ss * (1.0f / Ee) - mu * mu;
  const float rstd = rsqrtf(var + 1e-5f);
  const float4 sc = ((const float4*)scale)[tid];
  const float4 bi = ((const float4*)bias)[tid];
  ushort4 o;
  o.x = f2bf((v.x - mu) * rstd * sc.x + bi.x);
  o.y = f2bf((v.y - mu) * rstd * sc.y + bi.y);
  o.z = f2bf((v.z - mu) * rstd * sc.z + bi.z);
  o.w = f2bf((v.w - mu) * rstd * sc.w + bi.w);
  ((ushort4*)(h + (size_t)row * Ee))[tid] = o;
}

// ================= TLP-first GEMM: C = A @ B^T (+epilogue) ==================
// Tile BM x BN = (AM*32) x (AN*32); 4 waves in 2x2, each (AM*16)x(AN*16).
// BK=32. 2-deep ring, small LDS (<=24KB) -> 5-6 blocks/CU resident.
// Simple loop: STAGE(t+1) -> ds_read(t) -> MFMA(t) -> vmcnt(0) -> barrier.
// Cross-BLOCK TLP (the lever rounds 2-6 never had) hides the drain latency.
// EPI: 0 = QKV split (+bias, q*0.125 -> [B,H,S,D] bf16)
//      1 = +bias +resid(fp32) -> fp32
//      2 = gelu(+bias) -> bf16
template <int EPI, int AM, int AN>
__global__ __launch_bounds__(256, 5) void gemm3(
    const u16* __restrict__ A, const u16* __restrict__ Bw,
    const float* __restrict__ bias, const float* __restrict__ resid,
    float* __restrict__ outf, u16* __restrict__ outb,
    u16* __restrict__ q, u16* __restrict__ k, u16* __restrict__ v,
    int N, int K) {
  constexpr int BM = AM * 32, BN = AN * 32;
  constexpr int GA = BM / 64, GB = BN / 64;     // gload16 per thread per tile
  __shared__ u16 As[2][BM * 32];
  __shared__ u16 Bs[2][BN * 32];
  const int tid = threadIdx.x;
  const int w = tid >> 6, ln = tid & 63;
  const int lr = ln & 15, lg = ln >> 4;
  const int wr = w >> 1, wc = w & 1;

  // XCD bijective block swizzle (all grids here have nwg % 8 == 0)
  const int nwg = gridDim.x * gridDim.y;
  const int bid = blockIdx.y * gridDim.x + blockIdx.x;
  const int sid = (bid & 7) * (nwg >> 3) + (bid >> 3);
  const int bx = sid % gridDim.x, by = sid / gridDim.x;
  const int tm = by * BM, tn = bx * BN;

  f32x4 acc[AM][AN];
  f32x4 zero4 = {0.f, 0.f, 0.f, 0.f};
#pragma unroll
  for (int i = 0; i < AM; ++i)
#pragma unroll
    for (int j = 0; j < AN; ++j) acc[i][j] = zero4;

  // staging: granule g -> LDS row g>>2, 16B slot g&3 (linear dest);
  // global source slot pre-swizzled: slot ^ (row&3)  (both-sides rule)
  const int r0 = tid >> 2;
  const int cs = ((tid & 3) ^ (r0 & 3)) * 8;    // (row+64)&3 == row&3
  const u16* aP[GA];
  const u16* bP[GB];
#pragma unroll
  for (int i = 0; i < GA; ++i) aP[i] = A + (size_t)(tm + r0 + i * 64) * K + cs;
#pragma unroll
  for (int i = 0; i < GB; ++i) bP[i] = Bw + (size_t)(tn + r0 + i * 64) * K + cs;

  auto STAGE = [&](int buf, int k0) {
#pragma unroll
    for (int i = 0; i < GA; ++i)
      gload16(aP[i] + k0, &As[buf][(tid + i * 256) * 8]);
#pragma unroll
    for (int i = 0; i < GB; ++i)
      gload16(bP[i] + k0, &Bs[buf][(tid + i * 256) * 8]);
  };

  const int fsl = (lg ^ (lr & 3)) << 3;   // swizzled 16B slot on read
  const int nt = K >> 5;
  STAGE(0, 0);
  asm volatile("s_waitcnt vmcnt(0)" ::: "memory");
  __builtin_amdgcn_s_barrier();

  for (int t = 0; t < nt; ++t) {
    if (t + 1 < nt) STAGE((t + 1) & 1, (t + 1) << 5);   // into the other buffer
    const u16* Ab = &As[t & 1][0];
    const u16* Bbuf = &Bs[t & 1][0];
    bf16x8 af[AM], bf[AN];
#pragma unroll
    for (int mi = 0; mi < AM; ++mi)
      af[mi] = *(const bf16x8*)&Ab[(wr * AM * 16 + mi * 16 + lr) * 32 + fsl];
#pragma unroll
    for (int ni = 0; ni < AN; ++ni)
      bf[ni] = *(const bf16x8*)&Bbuf[(wc * AN * 16 + ni * 16 + lr) * 32 + fsl];
#pragma unroll
    for (int mi = 0; mi < AM; ++mi)
#pragma unroll
      for (int ni = 0; ni < AN; ++ni)
        acc[mi][ni] = MFMA(af[mi], bf[ni], acc[mi][ni]);
    // own stage(t+1) landed; barrier -> everyone's landed & frags(t) consumed
    asm volatile("s_waitcnt vmcnt(0)" ::: "memory");
    __builtin_amdgcn_s_barrier();
  }

  // ---- epilogue
#pragma unroll
  for (int mi = 0; mi < AM; ++mi) {
#pragma unroll
    for (int ni = 0; ni < AN; ++ni) {
      const int gc = tn + wc * AN * 16 + ni * 16 + lr;
#pragma unroll
      for (int j = 0; j < 4; ++j) {
        const int gr = tm + wr * AM * 16 + mi * 16 + lg * 4 + j;
        float val = acc[mi][ni][j] + bias[gc];
        if constexpr (EPI == 0) {
          const int which = gc >> 10, hh = (gc >> 6) & 15, dd = gc & 63;
          const int bb2 = gr >> 10, ss2 = gr & 1023;
          const size_t dst = ((size_t)(bb2 * 16 + hh) * 1024 + ss2) * 64 + dd;
          if (which == 0)      q[dst] = f2bf(val * 0.125f);   // 1/sqrt(64)
          else if (which == 1) k[dst] = f2bf(val);
          else                 v[dst] = f2bf(val);
        } else if constexpr (EPI == 1) {
          const size_t idx = (size_t)gr * N + gc;
          outf[idx] = val + resid[idx];
        } else {
          outb[(size_t)gr * N + gc] = f2bf(gelu_tanh(val));
        }
      }
    }
  }
}

// ---------- flash attention (no mask). Q pre-scaled. [B,H,S,D] bf16 in ------
__global__ __launch_bounds__(256) void attn_kernel(const u16* __restrict__ qg,
                                                   const u16* __restrict__ kg,
                                                   const u16* __restrict__ vg,
                                                   u16* __restrict__ ao) {
  __shared__ u16 Qs[64 * 64], Ks[64 * 64], Vt[64 * 64], Ps[64 * 64];
  const int tid = threadIdx.x;
  const int w = tid >> 6, ln = tid & 63;
  const int lr = ln & 15, lg = ln >> 4;
  const int bh = blockIdx.y;
  const int q0 = blockIdx.x * 64;
  const size_t head = (size_t)bh * (Ss * Dd);

  { // stage Q (swizzled)
    const u16* src = qg + head + (size_t)q0 * Dd;
#pragma unroll
    for (int i = 0; i < 2; ++i) {
      const int gi = i * 256 + tid, row = gi >> 3, g = gi & 7;
      *(uint4*)&Qs[row * 64 + ((g ^ (row & 7)) << 3)] = *(const uint4*)(src + gi * 8);
    }
  }

  f32x4 zero4 = {0.f, 0.f, 0.f, 0.f};
  f32x4 acc_o[4] = {zero4, zero4, zero4, zero4};
  float mrow[4] = {-1e30f, -1e30f, -1e30f, -1e30f};
  float lrow[4] = {0.f, 0.f, 0.f, 0.f};

  for (int kt = 0; kt < 16; ++kt) {
    __syncthreads();
    const u16* ksrc = kg + head + (size_t)kt * 64 * Dd;
    const u16* vsrc = vg + head + (size_t)kt * 64 * Dd;
#pragma unroll
    for (int i = 0; i < 2; ++i) {
      const int gi = i * 256 + tid, row = gi >> 3, g = gi & 7;
      *(uint4*)&Ks[row * 64 + ((g ^ (row & 7)) << 3)] = *(const uint4*)(ksrc + gi * 8);
    }
#pragma unroll
    for (int i = 0; i < 2; ++i) {
      const int kv = i * 32 + (tid >> 3), d0 = (tid & 7) * 8;
      uint4 dv = *(const uint4*)(vsrc + (size_t)kv * Dd + d0);
      const u16* pv = (const u16*)&dv;
#pragma unroll
      for (int j = 0; j < 8; ++j) {
        const int dd = d0 + j;
        Vt[dd * 64 + (((kv >> 3) ^ (dd & 7)) << 3) + (kv & 7)] = pv[j];
      }
    }
    __syncthreads();

    bf16x8 aq[2];
#pragma unroll
    for (int kk = 0; kk < 2; ++kk)
      aq[kk] = *(const bf16x8*)&Qs[swz(w * 16 + lr, kk * 32 + lg * 8)];
    f32x4 sa[4];
#pragma unroll
    for (int kf = 0; kf < 4; ++kf) {
      f32x4 s = zero4;
#pragma unroll
      for (int kk = 0; kk < 2; ++kk) {
        bf16x8 bk = *(const bf16x8*)&Ks[swz(kf * 16 + lr, kk * 32 + lg * 8)];
        s = MFMA(aq[kk], bk, s);
      }
      sa[kf] = s;
    }

#pragma unroll
    for (int j = 0; j < 4; ++j) {
      float mx = fmaxf(fmaxf(sa[0][j], sa[1][j]), fmaxf(sa[2][j], sa[3][j]));
      mx = fmaxf(mx, __shfl_xor(mx, 1, 64));
      mx = fmaxf(mx, __shfl_xor(mx, 2, 64));
      mx = fmaxf(mx, __shfl_xor(mx, 4, 64));
      mx = fmaxf(mx, __shfl_xor(mx, 8, 64));
      const float nm = fmaxf(mrow[j], mx);
      const float corr = __expf(mrow[j] - nm);
      mrow[j] = nm;
      float ssum = 0.f;
#pragma unroll
      for (int kf = 0; kf < 4; ++kf) {
        const float p = __expf(sa[kf][j] - nm);
        sa[kf][j] = p;
        ssum += p;
      }
      ssum += __shfl_xor(ssum, 1, 64);
      ssum += __shfl_xor(ssum, 2, 64);
      ssum += __shfl_xor(ssum, 4, 64);
      ssum += __shfl_xor(ssum, 8, 64);
      lrow[j] = lrow[j] * corr + ssum;
#pragma unroll
      for (int df = 0; df < 4; ++df) acc_o[df][j] *= corr;
    }

#pragma unroll
    for (int kf = 0; kf < 4; ++kf)
#pragma unroll
      for (int j = 0; j < 4; ++j)
        Ps[swz(w * 16 + lg * 4 + j, kf * 16 + lr)] = f2bf(sa[kf][j]);

    __syncthreads();

    bf16x8 ap[2];
#pragma unroll
    for (int kk = 0; kk < 2; ++kk)
      ap[kk] = *(const bf16x8*)&Ps[swz(w * 16 + lr, kk * 32 + lg * 8)];
#pragma unroll
    for (int df = 0; df < 4; ++df) {
#pragma unroll
      for (int kk = 0; kk < 2; ++kk) {
        bf16x8 bv = *(const bf16x8*)&Vt[swz(df * 16 + lr, kk * 32 + lg * 8)];
        acc_o[df] = MFMA(ap[kk], bv, acc_o[df]);
      }
    }
  }

  const int b = bh >> 4, h = bh & 15;
#pragma unroll
  for (int df = 0; df < 4; ++df) {
#pragma unroll
    for (int j = 0; j < 4; ++j) {
      const int srow = q0 + w * 16 + lg * 4 + j;
      const int e = h * 64 + df * 16 + lr;
      ao[((size_t)b * Ss + srow) * Ee + e] = f2bf(acc_o[df][j] / lrow[j]);
    }
  }
}

// ---------- launcher ----------
extern "C" void kernel_launch(void* const* d_in, const int* in_sizes, int n_in,
                              void* d_out, int out_size, void* d_ws, size_t ws_size,
                              hipStream_t stream) {
  const float* x      = (const float*)d_in[0];
  const float* ln1_s  = (const float*)d_in[1];
  const float* ln1_b  = (const float*)d_in[2];
  const float* w_attn = (const float*)d_in[3];
  const float* b_attn = (const float*)d_in[4];
  const float* w_proj = (const float*)d_in[5];
  const float* b_proj = (const float*)d_in[6];
  const float* ln2_s  = (const float*)d_in[7];
  const float* ln2_b  = (const float*)d_in[8];
  const float* w_fc   = (const float*)d_in[9];
  const float* b_fc   = (const float*)d_in[10];
  const float* w_proj2= (const float*)d_in[11];
  const float* b_proj2= (const float*)d_in[12];
  float* out = (float*)d_out;

  char* base = (char*)d_ws;
  size_t off = 0;
  auto alloc = [&](size_t bytes) { char* p = base + off; off += bytes; return p; };
  u16* wA   = (u16*)alloc((size_t)3 * Ee * Ee * 2);  // 6 MB
  u16* wP   = (u16*)alloc((size_t)Ee * Ee * 2);      // 2 MB
  u16* wF   = (u16*)alloc((size_t)Ff * Ee * 2);      // 8 MB
  u16* wP2  = (u16*)alloc((size_t)Ee * Ff * 2);      // 8 MB
  u16* h1   = (u16*)alloc((size_t)Mm * Ee * 2);      // 8 MB (reused as h2)
  u16* qws  = (u16*)alloc((size_t)Mm * Ee * 2);      // 8 MB (q; mfc alias start)
  u16* kws  = (u16*)alloc((size_t)Mm * Ee * 2);      // 8 MB (k)
  u16* vws  = (u16*)alloc((size_t)Mm * Ee * 2);      // 8 MB (v)
  u16* aws  = (u16*)alloc((size_t)Mm * Ee * 2);      // 8 MB (attn out)
  float* x1 = (float*)alloc((size_t)Mm * Ee * 4);    // 16 MB
  u16* mfc  = qws;  // [4096,4096] bf16 aliases q/k/v/ao (all dead by then)

  // weights -> bf16 (every call; deterministic)
  cvt_bf16<<<3 * Ee * Ee / 2048, 256, 0, stream>>>(w_attn, wA, 3 * Ee * Ee);
  cvt_bf16<<<Ee * Ee / 2048, 256, 0, stream>>>(w_proj, wP, Ee * Ee);
  cvt_bf16<<<Ff * Ee / 2048, 256, 0, stream>>>(w_fc, wF, Ff * Ee);
  cvt_bf16<<<Ee * Ff / 2048, 256, 0, stream>>>(w_proj2, wP2, Ee * Ff);

  // LN1 -> h1
  ln_kernel<<<Mm, 256, 0, stream>>>(x, ln1_s, ln1_b, h1);
  // QKV GEMM: [4096,1024]@[1024,3072]^T -> q,k,v [B,H,S,D]  (128x64 tiles, 1536 blocks)
  gemm3<0, 4, 2><<<dim3(48, 32), 256, 0, stream>>>(h1, wA, b_attn, nullptr,
                                                   nullptr, nullptr, qws, kws, vws,
                                                   3 * Ee, Ee);
  // attention
  attn_kernel<<<dim3(16, 64), 256, 0, stream>>>(qws, kws, vws, aws);
  // proj + residual -> x1 (fp32)  (64x64 tiles, 1024 blocks)
  gemm3<1, 2, 2><<<dim3(16, 64), 256, 0, stream>>>(aws, wP, b_proj, x,
                                                   x1, nullptr, nullptr, nullptr, nullptr,
                                                   Ee, Ee);
  // LN2 -> h1 (as h2)
  ln_kernel<<<Mm, 256, 0, stream>>>(x1, ln2_s, ln2_b, h1);
  // fc + gelu -> mfc (bf16)  (128x64 tiles, 2048 blocks)
  gemm3<2, 4, 2><<<dim3(64, 32), 256, 0, stream>>>(h1, wF, b_fc, nullptr,
                                                   nullptr, mfc, nullptr, nullptr, nullptr,
                                                   Ff, Ee);
  // proj2 + residual -> out (fp32)  (64x64 tiles, 1024 blocks)
  gemm3<1, 2, 2><<<dim3(16, 64), 256, 0, stream>>>(mfc, wP2, b_proj2, x1,
                                                   out, nullptr, nullptr, nullptr, nullptr,
                                                   Ee, Ff);
}